// Round 5
// baseline (63.211 us; speedup 1.0000x reference)
//
#include <hip/hip_runtime.h>

#define F_BINS  257
#define T_STEPS 65536
#define N_ACT   256
#define GT_PITCH 296   // bf16 elems/row of Gt; 592 B = 37*16 -> frags 16B-aligned
#define TM      128    // t-columns per block (4 waves x 32)
#define NBLK    512    // T_STEPS / TM
#define XO_CHUNK 8224  // (257*65536/4) float4 / 512 blocks, exact

typedef float f32x4 __attribute__((ext_vector_type(4)));
typedef short s16x8 __attribute__((ext_vector_type(8)));
typedef unsigned u32x4 __attribute__((ext_vector_type(4)));

// ws layout:
//   [0]      double Sc        (correction sum)
//   [8]      double Sb        (sum of x_out^2)
//   [16384]  unsigned maskp[NBLK*8]
//   [65536]  ushort Gt[256*GT_PITCH]   (G^T bf16, zero-pad f>=257)

__device__ __forceinline__ unsigned short f2bf_rne(float x) {
  unsigned u = __builtin_bit_cast(unsigned, x);
  return (unsigned short)((u + 0x7FFFu + ((u >> 16) & 1u)) >> 16);
}
__device__ __forceinline__ unsigned pack_bf(float hi, float lo) {
  return __builtin_amdgcn_perm(__builtin_bit_cast(unsigned, hi),
                               __builtin_bit_cast(unsigned, lo), 0x07060302u);
}

// ---------------------------------------------------------------------------
__global__ __launch_bounds__(256) void k_prep(const float* __restrict__ G,
                                              unsigned short* __restrict__ Gt) {
  __shared__ float tile[16][17];
  const int tx = threadIdx.x, ty = threadIdx.y;
  const int a0 = blockIdx.x * 16, f0 = blockIdx.y * 16;
  const int f = f0 + ty;
  tile[ty][tx] = (f < F_BINS) ? G[f * N_ACT + (a0 + tx)] : 0.f;
  __syncthreads();
  const int fw = f0 + tx;
  if (fw < GT_PITCH) Gt[(a0 + ty) * GT_PITCH + fw] = f2bf_rne(tile[tx][ty]);
}

// ---------------------------------------------------------------------------
// Barrier-free GEMM: A (xs) -> registers once (bf16 frags, 2 t-tiles/wave);
// B (Gt) fragments read directly from L2-resident global per MFMA. Argmax
// computed in two action-halves to keep acc at 64 VGPR. Then fused xo^2.
// ---------------------------------------------------------------------------
__global__ __launch_bounds__(256, 2) void k_gemm(
    const float* __restrict__ xs, const float* __restrict__ xo,
    const unsigned short* __restrict__ Gt,
    unsigned* __restrict__ maskp, double* __restrict__ Sb) {
  const int tid  = threadIdx.x;
  const int lane = tid & 63;
  const int wv   = tid >> 6;
  const int g    = lane >> 4;
  const int r16  = lane & 15;
  const int t0   = blockIdx.x * TM;
  const int trow = t0 + wv * 32 + r16;   // A-tile 0 row; tile 1 = +16

  __shared__ unsigned lmask[8];
  __shared__ double sd[4];
  if (tid < 8) lmask[tid] = 0u;

  // ---- A: load xs once, pack to bf16 fragments (depth-2 pipeline) ----
  // af[tau][kk] = A[row=r16][k=8g+j] = xs[f=32kk+8g+j][trow+16tau]
#define LOADA(p, kkv)                                                        \
  {                                                                          \
    _Pragma("unroll") for (int tau = 0; tau < 2; ++tau)                      \
    _Pragma("unroll") for (int j = 0; j < 8; ++j) {                          \
      int f = 32 * (kkv) + 8 * g + j;                                        \
      if ((kkv) == 8) f = f > 256 ? 256 : f; /* Gt zero-pad kills garbage */ \
      va[p][tau][j] = xs[(size_t)f * T_STEPS + trow + 16 * tau];             \
    }                                                                        \
  }
#define PACK8(v) __builtin_bit_cast(s16x8, (u32x4){                          \
      pack_bf((v)[1], (v)[0]), pack_bf((v)[3], (v)[2]),                      \
      pack_bf((v)[5], (v)[4]), pack_bf((v)[7], (v)[6])})

  s16x8 af[2][9];
  float va[2][2][8];
  LOADA(0, 0);
  LOADA(1, 1);
#pragma unroll
  for (int kk = 0; kk < 9; ++kk) {
    const int p = kk & 1;
    af[0][kk] = PACK8(va[p][0]);
    af[1][kk] = PACK8(va[p][1]);
    if (kk + 2 <= 8) LOADA(p, kk + 2);
  }
#undef LOADA

  // ---- main: two action-halves of 128; B frags straight from L2 ----
  float bv[2][4]; int bc[2][4];
#pragma unroll
  for (int tau = 0; tau < 2; ++tau)
#pragma unroll
    for (int q = 0; q < 4; ++q) { bv[tau][q] = -__builtin_inff(); bc[tau][q] = 0; }

  const unsigned short* gB = Gt + (size_t)r16 * GT_PITCH + 8 * g;

#pragma unroll 1
  for (int h = 0; h < 2; ++h) {
    f32x4 acc[2][8];
#pragma unroll
    for (int n = 0; n < 8; ++n) {
      acc[0][n] = (f32x4){0.f, 0.f, 0.f, 0.f};
      acc[1][n] = (f32x4){0.f, 0.f, 0.f, 0.f};
    }
    const unsigned short* gH = gB + (size_t)(8 * h) * 16 * GT_PITCH;
#pragma unroll
    for (int kk = 0; kk < 9; ++kk) {
#pragma unroll
      for (int n = 0; n < 8; ++n) {
        const s16x8 bfr =
            *(const s16x8*)(gH + (size_t)n * 16 * GT_PITCH + kk * 32);
        acc[0][n] = __builtin_amdgcn_mfma_f32_16x16x32_bf16(af[0][kk], bfr,
                                                            acc[0][n], 0, 0, 0);
        acc[1][n] = __builtin_amdgcn_mfma_f32_16x16x32_bf16(af[1][kk], bfr,
                                                            acc[1][n], 0, 0, 0);
      }
    }
    // in-lane argmax update (ascending action => first-min tie-break kept)
#pragma unroll
    for (int n = 0; n < 8; ++n) {
      const int c = 16 * (8 * h + n) + r16;
#pragma unroll
      for (int tau = 0; tau < 2; ++tau)
#pragma unroll
        for (int q = 0; q < 4; ++q)
          if (acc[tau][n][q] > bv[tau][q]) { bv[tau][q] = acc[tau][n][q]; bc[tau][q] = c; }
    }
  }

  // cross-lane (over r16) argmax; t = t0+32wv+16tau+4g+q identical across r16
#pragma unroll
  for (int m = 1; m <= 8; m <<= 1) {
#pragma unroll
    for (int tau = 0; tau < 2; ++tau)
#pragma unroll
      for (int q = 0; q < 4; ++q) {
        const float ov = __shfl_xor(bv[tau][q], m);
        const int   oc = __shfl_xor(bc[tau][q], m);
        if (ov > bv[tau][q] || (ov == bv[tau][q] && oc < bc[tau][q])) {
          bv[tau][q] = ov; bc[tau][q] = oc;
        }
      }
  }
  __syncthreads();   // lmask zero-init visible
  if (r16 == 0) {
#pragma unroll
    for (int tau = 0; tau < 2; ++tau)
#pragma unroll
      for (int q = 0; q < 4; ++q)
        atomicOr(&lmask[bc[tau][q] >> 5], 1u << (bc[tau][q] & 31));
  }
  __syncthreads();
  if (tid < 8) maskp[blockIdx.x * 8 + tid] = lmask[tid];

  // ---- fused sum of x_out^2: contiguous per-block float4 chunk ----
  const float4* xo4 = (const float4*)xo;
  const int base = blockIdx.x * XO_CHUNK;
  double ds = 0.0;
#pragma unroll 4
  for (int i = tid; i < XO_CHUNK; i += 256) {
    const float4 v = xo4[base + i];
    ds += (double)fmaf(v.x, v.x, v.y * v.y) + (double)fmaf(v.z, v.z, v.w * v.w);
  }
#pragma unroll
  for (int off = 32; off; off >>= 1) ds += __shfl_down(ds, off);
  if (lane == 0) sd[wv] = ds;
  __syncthreads();
  if (tid == 0) atomicAdd(Sb, sd[0] + sd[1] + sd[2] + sd[3]);
}

// ---------------------------------------------------------------------------
__global__ __launch_bounds__(256) void k_corr(
    const float* __restrict__ xs, const float* __restrict__ xo,
    const float* __restrict__ G, const unsigned* __restrict__ maskp,
    double* __restrict__ Sc) {
  __shared__ unsigned m8[8];
  const int tid = threadIdx.x;
  if (tid < 8) m8[tid] = 0u;
  __syncthreads();
  unsigned m = 0;
  for (int b = tid >> 3; b < NBLK; b += 32) m |= maskp[b * 8 + (tid & 7)];
  atomicOr(&m8[tid & 7], m);
  __syncthreads();
  const int f = blockIdx.x;
  const int a = tid;
  const bool sel = (m8[a >> 5] >> (a & 31)) & 1u;
  const float gv  = G[f * N_ACT + a];
  const float xsv = xs[f * T_STEPS + a];
  const float xov = xo[f * T_STEPS + a];
  const float gx  = gv * xsv;
  double acc = sel ? (double)(gx * (gx - 2.f * xov)) : 0.0;
#pragma unroll
  for (int off = 32; off; off >>= 1) acc += __shfl_down(acc, off);
  __shared__ double sdc[4];
  if ((tid & 63) == 0) sdc[tid >> 6] = acc;
  __syncthreads();
  if (tid == 0) atomicAdd(Sc, sdc[0] + sdc[1] + sdc[2] + sdc[3]);
}

__global__ void k_final(const double* __restrict__ Sb,
                        const double* __restrict__ Sc,
                        float* __restrict__ out) {
  out[0] = (float)((Sb[0] + Sc[0]) / ((double)F_BINS * (double)T_STEPS));
}

extern "C" void kernel_launch(void* const* d_in, const int* in_sizes, int n_in,
                              void* d_out, int out_size, void* d_ws, size_t ws_size,
                              hipStream_t stream) {
  const float* x_out    = (const float*)d_in[0];
  const float* x_source = (const float*)d_in[1];
  // d_in[2] (x_clean) is dead: argmin_a(clean_sum - proj) == argmax_a proj
  const float* G        = (const float*)d_in[3];

  char* ws = (char*)d_ws;
  double*         Sc    = (double*)ws;
  double*         Sb    = (double*)(ws + 8);
  unsigned*       maskp = (unsigned*)(ws + 16384);
  unsigned short* Gt    = (unsigned short*)(ws + 65536);

  hipMemsetAsync(d_ws, 0, 64, stream);
  k_prep <<<dim3(16, 19), dim3(16, 16), 0, stream>>>(G, Gt);
  k_gemm <<<NBLK, 256, 0, stream>>>(x_source, x_out, Gt, maskp, Sb);
  k_corr <<<F_BINS, 256, 0, stream>>>(x_source, x_out, G, maskp, Sc);
  k_final<<<1, 1, 0, stream>>>(Sb, Sc, (float*)d_out);
}